// Round 9
// baseline (185.830 us; speedup 1.0000x reference)
//
#include <hip/hip_runtime.h>

// ============================================================================
// 8-launch pipeline recomposed STRICTLY from previously-PASSed kernels:
//  - prep_kernel   : round-4 form (PASSED @180us)   -- all converts + im2col
//  - gemm_bf16     : round-3 form (PASSED @192us)   -- 128x128 MFMA tiles
//  - ln_kernel     : round-3 form (4-partial reduce + LN)
//  - kvpost_kernel : round-3 form (4-partial reduce + K/V layout)
//  - attn_kernel   : round-3/4 form (flash-style, scrambled output layout)
// Conv bias skipped (constant over LN axis -> cancelled exactly by LN).
// ============================================================================

#define B_    2
#define NTOK  4096
#define C_    512
#define MSP   1024

typedef __attribute__((ext_vector_type(8))) short short8;
typedef __attribute__((ext_vector_type(4))) short short4v;
typedef __attribute__((ext_vector_type(4))) float f32x4;

__device__ __forceinline__ unsigned short f2bf(float f) {
    unsigned u = __builtin_bit_cast(unsigned, f);
    u += 0x7FFFu + ((u >> 16) & 1u);            // RNE
    return (unsigned short)(u >> 16);
}

// ---------------------------------------------------------------------------
// Fused prep (one launch, 640 blocks) — round-4 verbatim:
//  [0,128)   : x fp32 -> xb bf16 (straight) + xg im2col bf16
//  [128,192) : Wq   512x512  -> WqT   (transpose-convert)
//  [192,448) : Wkv 1024x1024 -> WkvT  (transpose-convert)
//  [448,512) : Wproj 512x512 -> WprojT(transpose-convert)
//  [512,640) : Wconv -> WcB straight convert
// ---------------------------------------------------------------------------
__device__ __forceinline__ void tconv_dev(
    const float* __restrict__ in, unsigned short* __restrict__ out,
    int R, int C, int bx, int by, int tid, float (*T)[68])
{
    const int r0 = by * 64, c0 = bx * 64;
    const int i = tid >> 2, jp = tid & 3;
    #pragma unroll
    for (int q = 0; q < 4; ++q) {
        float4 v = *(const float4*)(in + (long)(r0 + i) * C + c0 + jp * 16 + q * 4);
        *(float4*)&T[i][jp * 16 + q * 4] = v;
    }
    __syncthreads();
    #pragma unroll
    for (int q = 0; q < 4; ++q) {
        short4v o;
        #pragma unroll
        for (int l = 0; l < 4; ++l)
            o[l] = (short)f2bf(T[jp * 16 + q * 4 + l][i]);
        *(short4v*)(out + (long)(c0 + i) * R + r0 + jp * 16 + q * 4) = o;
    }
}

__global__ __launch_bounds__(256) void prep_kernel(
    const float* __restrict__ x, unsigned short* __restrict__ xg,
    unsigned short* __restrict__ xb,
    const float* __restrict__ Wq,    unsigned short* __restrict__ WqT,
    const float* __restrict__ Wkv,   unsigned short* __restrict__ WkvT,
    const float* __restrict__ Wproj, unsigned short* __restrict__ WprojT,
    const float* __restrict__ Wconv, unsigned short* __restrict__ WcB)
{
    __shared__ float T[64][68];
    const int bx = blockIdx.x;
    const int tid = threadIdx.x;

    if (bx < 128) {
        const int b = bx >> 6;
        const int ty = tid >> 4, tx = tid & 15;
        const int m = (bx & 63) * 16 + ty;
        const int my = m >> 5, mx = m & 31;
        const float* xsrc = x + (long)b * NTOK * C_;
        unsigned short* op = xg + ((long)b * MSP + m) * 2048;
        unsigned short* xo = xb + (long)b * NTOK * C_;
        const int n00 = (2 * my) * 64 + 2 * mx;
        const int n01 = n00 + 1, n10 = n00 + 64, n11 = n00 + 65;
        const float* p00 = xsrc + (long)n00 * C_;
        const float* p01 = xsrc + (long)n01 * C_;
        const float* p10 = xsrc + (long)n10 * C_;
        const float* p11 = xsrc + (long)n11 * C_;
        for (int c0 = tx * 4; c0 < C_; c0 += 64) {
            float4 v0 = *(const float4*)(p00 + c0);
            float4 v1 = *(const float4*)(p01 + c0);
            float4 v2 = *(const float4*)(p10 + c0);
            float4 v3 = *(const float4*)(p11 + c0);
            short8 o0, o1;
            o0[0] = (short)f2bf(v0.x); o0[1] = (short)f2bf(v1.x);
            o0[2] = (short)f2bf(v2.x); o0[3] = (short)f2bf(v3.x);
            o0[4] = (short)f2bf(v0.y); o0[5] = (short)f2bf(v1.y);
            o0[6] = (short)f2bf(v2.y); o0[7] = (short)f2bf(v3.y);
            o1[0] = (short)f2bf(v0.z); o1[1] = (short)f2bf(v1.z);
            o1[2] = (short)f2bf(v2.z); o1[3] = (short)f2bf(v3.z);
            o1[4] = (short)f2bf(v0.w); o1[5] = (short)f2bf(v1.w);
            o1[6] = (short)f2bf(v2.w); o1[7] = (short)f2bf(v3.w);
            *(short8*)(op + 4 * c0) = o0;
            *(short8*)(op + 4 * c0 + 8) = o1;
            short4v s;
            s[0] = (short)f2bf(v0.x); s[1] = (short)f2bf(v0.y);
            s[2] = (short)f2bf(v0.z); s[3] = (short)f2bf(v0.w);
            *(short4v*)(xo + (long)n00 * C_ + c0) = s;
            s[0] = (short)f2bf(v1.x); s[1] = (short)f2bf(v1.y);
            s[2] = (short)f2bf(v1.z); s[3] = (short)f2bf(v1.w);
            *(short4v*)(xo + (long)n01 * C_ + c0) = s;
            s[0] = (short)f2bf(v2.x); s[1] = (short)f2bf(v2.y);
            s[2] = (short)f2bf(v2.z); s[3] = (short)f2bf(v2.w);
            *(short4v*)(xo + (long)n10 * C_ + c0) = s;
            s[0] = (short)f2bf(v3.x); s[1] = (short)f2bf(v3.y);
            s[2] = (short)f2bf(v3.z); s[3] = (short)f2bf(v3.w);
            *(short4v*)(xo + (long)n11 * C_ + c0) = s;
        }
    } else if (bx < 192) {
        int sb = bx - 128;
        tconv_dev(Wq, WqT, 512, 512, sb & 7, sb >> 3, tid, T);
    } else if (bx < 448) {
        int sb = bx - 192;
        tconv_dev(Wkv, WkvT, 1024, 1024, sb & 15, sb >> 4, tid, T);
    } else if (bx < 512) {
        int sb = bx - 448;
        tconv_dev(Wproj, WprojT, 512, 512, sb & 7, sb >> 3, tid, T);
    } else {
        int base = (bx - 512) * 256 + tid;   // 0..32767
        #pragma unroll
        for (int j = 0; j < 4; ++j) {
            int i = base + j * 32768;        // short8 index, 131072 total
            float4 a = ((const float4*)Wconv)[2 * i];
            float4 b = ((const float4*)Wconv)[2 * i + 1];
            short8 o;
            o[0] = (short)f2bf(a.x); o[1] = (short)f2bf(a.y);
            o[2] = (short)f2bf(a.z); o[3] = (short)f2bf(a.w);
            o[4] = (short)f2bf(b.x); o[5] = (short)f2bf(b.y);
            o[6] = (short)f2bf(b.z); o[7] = (short)f2bf(b.w);
            ((short8*)WcB)[i] = o;
        }
    }
}

// ---------------------------------------------------------------------------
// bf16 MFMA GEMM — round-3 verbatim. 128x128 tile, BK=64, 4 waves (2x2),
// wave tile 64x64 = 4x4 frags. C[row][col] = sum_k A[row][k] * BT[col][k].
// OMODE: 0 = fp32 partial store at Cv + z*M*ldc (split-K, no bias),
//        1 = bf16 store + col bias, 2 = fp32 store + col bias.
// ---------------------------------------------------------------------------
template<int OMODE>
__global__ __launch_bounds__(256) void gemm_bf16(
    const unsigned short* __restrict__ A, const unsigned short* __restrict__ BT,
    const float* __restrict__ bias, void* __restrict__ Cv,
    int M, int N, int Kc, int KS, int lda, int ldb, int ldc,
    long sAb, long sBb, long sCb)
{
    __shared__ unsigned short As[128][72];
    __shared__ unsigned short Bs[128][72];
    const int tid = threadIdx.x;
    const int z = blockIdx.z, b = z / KS, kc = z % KS;
    const int row0 = blockIdx.y * 128, col0 = blockIdx.x * 128;
    const unsigned short* Ap = A + b * sAb + (long)kc * Kc + (long)row0 * lda;
    const unsigned short* Bp = BT + b * sBb + (long)kc * Kc + (long)col0 * ldb;
    const int lane = tid & 63, wave = tid >> 6;
    const int wr = (wave >> 1) * 64, wc = (wave & 1) * 64;
    const int l15 = lane & 15, l4 = lane >> 4;

    f32x4 acc[4][4] = {};
    const int nk = Kc >> 6;
    for (int ks = 0; ks < nk; ++ks) {
        const int k0 = ks << 6;
        short8 ar[4], br[4];
        int rr[4], pp[4];
        #pragma unroll
        for (int i = 0; i < 4; ++i) {
            int chunk = tid + 256 * i;
            rr[i] = chunk >> 3; pp[i] = chunk & 7;
            ar[i] = *(const short8*)(Ap + (long)rr[i] * lda + k0 + pp[i] * 8);
            br[i] = *(const short8*)(Bp + (long)rr[i] * ldb + k0 + pp[i] * 8);
        }
        __syncthreads();   // prior reads of As/Bs complete
        #pragma unroll
        for (int i = 0; i < 4; ++i) {
            *(short8*)&As[rr[i]][pp[i] * 8] = ar[i];
            *(short8*)&Bs[rr[i]][pp[i] * 8] = br[i];
        }
        __syncthreads();
        #pragma unroll
        for (int kg = 0; kg < 2; ++kg) {
            short8 af[4], bf[4];
            #pragma unroll
            for (int mf = 0; mf < 4; ++mf)
                af[mf] = *(const short8*)&As[wr + mf * 16 + l15][kg * 32 + l4 * 8];
            #pragma unroll
            for (int nf = 0; nf < 4; ++nf)
                bf[nf] = *(const short8*)&Bs[wc + nf * 16 + l15][kg * 32 + l4 * 8];
            #pragma unroll
            for (int mf = 0; mf < 4; ++mf)
                #pragma unroll
                for (int nf = 0; nf < 4; ++nf)
                    acc[mf][nf] = __builtin_amdgcn_mfma_f32_16x16x32_bf16(
                        af[mf], bf[nf], acc[mf][nf], 0, 0, 0);
        }
    }
    // epilogue: C/D frag layout col = lane&15, row = (lane>>4)*4 + r  [verified]
    const int cb = col0 + wc + l15;
    const int rb = row0 + wr + l4 * 4;
    if (OMODE == 0) {
        float* C = (float*)Cv + (long)z * M * (long)ldc;
        #pragma unroll
        for (int mf = 0; mf < 4; ++mf)
            #pragma unroll
            for (int nf = 0; nf < 4; ++nf)
                #pragma unroll
                for (int i = 0; i < 4; ++i)
                    C[(long)(rb + mf * 16 + i) * ldc + cb + nf * 16] = acc[mf][nf][i];
    } else if (OMODE == 1) {
        unsigned short* C = (unsigned short*)Cv + sCb * b;
        #pragma unroll
        for (int nf = 0; nf < 4; ++nf) {
            float bv = bias[cb + nf * 16];
            #pragma unroll
            for (int mf = 0; mf < 4; ++mf)
                #pragma unroll
                for (int i = 0; i < 4; ++i)
                    C[(long)(rb + mf * 16 + i) * ldc + cb + nf * 16] =
                        f2bf(acc[mf][nf][i] + bv);
        }
    } else {
        float* C = (float*)Cv + sCb * b;
        #pragma unroll
        for (int nf = 0; nf < 4; ++nf) {
            float bv = bias[cb + nf * 16];
            #pragma unroll
            for (int mf = 0; mf < 4; ++mf)
                #pragma unroll
                for (int i = 0; i < 4; ++i)
                    C[(long)(rb + mf * 16 + i) * ldc + cb + nf * 16] =
                        acc[mf][nf][i] + bv;
        }
    }
}

// ---------------------------------------------------------------------------
// Fused 4-partial reduce + LayerNorm over m (1024) -> bf16 — round-3 verbatim.
// pconv[(b*4+kc)][512][1024]; one block per (b,c) row.
// ---------------------------------------------------------------------------
__global__ __launch_bounds__(256) void ln_kernel(
    const float* __restrict__ pconv, unsigned short* __restrict__ xwb,
    const float* __restrict__ gamma, const float* __restrict__ beta)
{
    __shared__ float red[256];
    const int tid = threadIdx.x;
    const int b = blockIdx.x >> 9, c = blockIdx.x & 511;
    const float* base = pconv + ((long)b * 4 * 512 + c) * 1024;
    const int m = tid * 4;
    float4 v = make_float4(0.f, 0.f, 0.f, 0.f);
    #pragma unroll
    for (int kc = 0; kc < 4; ++kc) {
        float4 t = *(const float4*)(base + (long)kc * 512 * 1024 + m);
        v.x += t.x; v.y += t.y; v.z += t.z; v.w += t.w;
    }
    red[tid] = v.x + v.y + v.z + v.w;
    __syncthreads();
    for (int off = 128; off > 0; off >>= 1) {
        if (tid < off) red[tid] += red[tid + off];
        __syncthreads();
    }
    float mu = red[0] * (1.0f / MSP);
    __syncthreads();
    float dx = v.x - mu, dy = v.y - mu, dz = v.z - mu, dw = v.w - mu;
    red[tid] = dx * dx + dy * dy + dz * dz + dw * dw;
    __syncthreads();
    for (int off = 128; off > 0; off >>= 1) {
        if (tid < off) red[tid] += red[tid + off];
        __syncthreads();
    }
    float rs = rsqrtf(red[0] * (1.0f / MSP) + 1e-5f);
    float4 g  = *(const float4*)(gamma + m);
    float4 be = *(const float4*)(beta + m);
    short4v o;
    o[0] = (short)f2bf(dx * rs * g.x + be.x);
    o[1] = (short)f2bf(dy * rs * g.y + be.y);
    o[2] = (short)f2bf(dz * rs * g.z + be.z);
    o[3] = (short)f2bf(dw * rs * g.w + be.w);
    *(short4v*)(xwb + (long)blockIdx.x * MSP + m) = o;
}

// ---------------------------------------------------------------------------
// Fused 4-partial reduce + kv post — round-3 verbatim:
// pkv[(b*4+kc)][512 m][1024] (+bkv) -> kbuf bf16 [b][m][512] (K)
// and vT bf16 [b][u][m] (V transposed). 64x64 tiles.
// ---------------------------------------------------------------------------
__global__ __launch_bounds__(256) void kvpost_kernel(
    const float* __restrict__ pkv, const float* __restrict__ bkv,
    unsigned short* __restrict__ kbuf, unsigned short* __restrict__ vT)
{
    __shared__ float T[64][68];
    const int tid = threadIdx.x;
    const int m0 = blockIdx.x * 64, u0 = blockIdx.y * 64, b = blockIdx.z;
    const float* base = pkv + (long)b * 4 * 512 * 1024;
    const int i = tid >> 2, jp = tid & 3;
    #pragma unroll
    for (int q = 0; q < 4; ++q) {
        int uc = u0 + jp * 16 + q * 4;
        float4 bb = *(const float4*)(bkv + uc);
        float4 v = bb;
        #pragma unroll
        for (int kc = 0; kc < 4; ++kc) {
            float4 t = *(const float4*)(base + (long)kc * 512 * 1024 + (long)(m0 + i) * 1024 + uc);
            v.x += t.x; v.y += t.y; v.z += t.z; v.w += t.w;
        }
        short4v o;
        o[0] = (short)f2bf(v.x); o[1] = (short)f2bf(v.y);
        o[2] = (short)f2bf(v.z); o[3] = (short)f2bf(v.w);
        *(short4v*)(kbuf + ((long)b * 512 + m0 + i) * 512 + uc) = o;
    }
    #pragma unroll
    for (int q = 0; q < 4; ++q) {
        int uc = u0 + jp * 16 + q * 4;
        float4 bb = *(const float4*)(bkv + 512 + uc);
        float4 v = bb;
        #pragma unroll
        for (int kc = 0; kc < 4; ++kc) {
            float4 t = *(const float4*)(base + (long)kc * 512 * 1024 + (long)(m0 + i) * 1024 + 512 + uc);
            v.x += t.x; v.y += t.y; v.z += t.z; v.w += t.w;
        }
        *(float4*)&T[i][jp * 16 + q * 4] = v;
    }
    __syncthreads();
    #pragma unroll
    for (int q = 0; q < 4; ++q) {
        short4v o;
        #pragma unroll
        for (int l = 0; l < 4; ++l)
            o[l] = (short)f2bf(T[jp * 16 + q * 4 + l][i]);
        *(short4v*)(vT + ((long)b * 512 + u0 + i) * 512 + m0 + jp * 16 + q * 4) = o;
    }
}

// ---------------------------------------------------------------------------
// Attention — round-3/4 verbatim. Block = 256 thr (4 waves), 128 q-rows,
// KV len 512 in 8 tiles of 64. No max-subtraction (logits bounded, exact).
// Output in the reference's transpose-reshape layout:
//   o2[b][(h*64+d)*8 + (n>>9)][n&511]
// ---------------------------------------------------------------------------
__global__ __launch_bounds__(256) void attn_kernel(
    const unsigned short* __restrict__ qb, const unsigned short* __restrict__ kbuf,
    const unsigned short* __restrict__ vT, unsigned short* __restrict__ o2)
{
    __shared__ unsigned short Qs[128][72];
    __shared__ unsigned short Ks[64][72];
    __shared__ unsigned short Vs[64][72];
    __shared__ unsigned short Ps[4][32][72];
    const int tid = threadIdx.x;
    const int b = blockIdx.y >> 3, h = blockIdx.y & 7;
    const int n0 = blockIdx.x * 128;
    const int lane = tid & 63, w = tid >> 6;
    const int l15 = lane & 15, l4 = lane >> 4;

    const unsigned short* Qg = qb + ((long)b * NTOK + n0) * 512 + h * 64;
    const unsigned short* Kg = kbuf + (long)b * 512 * 512 + h * 64;
    const unsigned short* Vg = vT + ((long)b * 512 + h * 64) * 512;

    #pragma unroll
    for (int it = 0; it < 4; ++it) {
        int chunk = tid + 256 * it;
        int r = chunk >> 3, p = chunk & 7;
        *(short8*)&Qs[r][p * 8] = *(const short8*)(Qg + (long)r * 512 + p * 8);
    }
    __syncthreads();
    short8 qa[2][2];
    #pragma unroll
    for (int mf = 0; mf < 2; ++mf)
        #pragma unroll
        for (int kg = 0; kg < 2; ++kg)
            qa[mf][kg] = *(const short8*)&Qs[w * 32 + mf * 16 + l15][kg * 32 + l4 * 8];

    f32x4 oacc[2][4] = {};
    float lsum[2][4] = {};

    for (int mt = 0; mt < 8; ++mt) {
        const int m0 = mt * 64;
        __syncthreads();
        #pragma unroll
        for (int it = 0; it < 2; ++it) {
            int chunk = tid + 256 * it;
            int r = chunk >> 3, p = chunk & 7;
            *(short8*)&Ks[r][p * 8] = *(const short8*)(Kg + (long)(m0 + r) * 512 + p * 8);
            *(short8*)&Vs[r][p * 8] = *(const short8*)(Vg + (long)r * 512 + m0 + p * 8);
        }
        __syncthreads();
        f32x4 s[2][4];
        #pragma unroll
        for (int nf = 0; nf < 4; ++nf) {
            short8 kb0 = *(const short8*)&Ks[nf * 16 + l15][l4 * 8];
            short8 kb1 = *(const short8*)&Ks[nf * 16 + l15][32 + l4 * 8];
            #pragma unroll
            for (int mf = 0; mf < 2; ++mf) {
                f32x4 zz = {};
                zz = __builtin_amdgcn_mfma_f32_16x16x32_bf16(qa[mf][0], kb0, zz, 0, 0, 0);
                zz = __builtin_amdgcn_mfma_f32_16x16x32_bf16(qa[mf][1], kb1, zz, 0, 0, 0);
                s[mf][nf] = zz;
            }
        }
        #pragma unroll
        for (int mf = 0; mf < 2; ++mf)
            #pragma unroll
            for (int nf = 0; nf < 4; ++nf)
                #pragma unroll
                for (int i = 0; i < 4; ++i) {
                    float pv = __expf(s[mf][nf][i] * 0.125f);
                    lsum[mf][i] += pv;
                    Ps[w][mf * 16 + l4 * 4 + i][nf * 16 + l15] = f2bf(pv);
                }
        #pragma unroll
        for (int mf = 0; mf < 2; ++mf) {
            short8 pa0 = *(const short8*)&Ps[w][mf * 16 + l15][l4 * 8];
            short8 pa1 = *(const short8*)&Ps[w][mf * 16 + l15][32 + l4 * 8];
            #pragma unroll
            for (int df = 0; df < 4; ++df) {
                short8 vb0 = *(const short8*)&Vs[df * 16 + l15][l4 * 8];
                short8 vb1 = *(const short8*)&Vs[df * 16 + l15][32 + l4 * 8];
                oacc[mf][df] = __builtin_amdgcn_mfma_f32_16x16x32_bf16(pa0, vb0, oacc[mf][df], 0, 0, 0);
                oacc[mf][df] = __builtin_amdgcn_mfma_f32_16x16x32_bf16(pa1, vb1, oacc[mf][df], 0, 0, 0);
            }
        }
    }
    #pragma unroll
    for (int mf = 0; mf < 2; ++mf)
        #pragma unroll
        for (int i = 0; i < 4; ++i) {
            float v = lsum[mf][i];
            v += __shfl_xor(v, 1, 64);
            v += __shfl_xor(v, 2, 64);
            v += __shfl_xor(v, 4, 64);
            v += __shfl_xor(v, 8, 64);
            lsum[mf][i] = 1.0f / v;
        }
    const int nhi = n0 >> 9;
    const int colb = (n0 & 511) + w * 32;
    #pragma unroll
    for (int mf = 0; mf < 2; ++mf)
        #pragma unroll
        for (int df = 0; df < 4; ++df) {
            int d = h * 64 + df * 16 + l15;
            long row = (long)b * NTOK + (long)d * 8 + nhi;
            short4v o;
            o[0] = (short)f2bf(oacc[mf][df][0] * lsum[mf][0]);
            o[1] = (short)f2bf(oacc[mf][df][1] * lsum[mf][1]);
            o[2] = (short)f2bf(oacc[mf][df][2] * lsum[mf][2]);
            o[3] = (short)f2bf(oacc[mf][df][3] * lsum[mf][3]);
            *(short4v*)(o2 + row * 512 + colb + mf * 16 + l4 * 4) = o;
        }
}

// ---------------------------------------------------------------------------
extern "C" void kernel_launch(void* const* d_in, const int* in_sizes, int n_in,
                              void* d_out, int out_size, void* d_ws, size_t ws_size,
                              hipStream_t stream)
{
    (void)in_sizes; (void)n_in; (void)out_size; (void)ws_size;
    const float* x     = (const float*)d_in[0];
    const float* Wq    = (const float*)d_in[1];
    const float* bq    = (const float*)d_in[2];
    const float* Wconv = (const float*)d_in[3];
    // d_in[4] = bconv: constant over LN axis -> exactly cancelled by LN; unused
    const float* gamma = (const float*)d_in[5];
    const float* beta  = (const float*)d_in[6];
    const float* Wkv   = (const float*)d_in[7];
    const float* bkv   = (const float*)d_in[8];
    const float* Wproj = (const float*)d_in[9];
    const float* bproj = (const float*)d_in[10];
    float* out = (float*)d_out;
    char* ws = (char*)d_ws;

    unsigned short* xb     = (unsigned short*)(ws);                  //  8 MB
    unsigned short* qbuf   = (unsigned short*)(ws + (8ul  << 20));   //  8 MB
    unsigned short* xg     = (unsigned short*)(ws + (16ul << 20));   //  8 MB
    unsigned short* o2     = xg;                                     //  overlay
    unsigned short* WqT    = (unsigned short*)(ws + (24ul << 20));   // 0.5 MB
    unsigned short* WcB    = (unsigned short*)(ws + (25ul << 20));   //  2 MB
    unsigned short* WkvT   = (unsigned short*)(ws + (27ul << 20));   //  2 MB
    unsigned short* WprojT = (unsigned short*)(ws + (29ul << 20));   // 0.5 MB
    float*          pconv  = (float*)         (ws + (30ul << 20));   // 16 MB
    unsigned short* xwb    = (unsigned short*)(ws + (46ul << 20));   //  2 MB
    float*          pkv    = (float*)         (ws + (48ul << 20));   // 16 MB
    unsigned short* kbuf   = (unsigned short*)(ws + (64ul << 20));   //  1 MB
    unsigned short* vTb    = (unsigned short*)(ws + (65ul << 20));   //  1 MB

    // all prep in one launch (round-4 form)
    prep_kernel<<<dim3(640), 256, 0, stream>>>(
        x, xg, xb, Wq, WqT, Wkv, WkvT, Wproj, WprojT, Wconv, WcB);

    // Q = x @ Wq + bq -> bf16 [8192][512]
    gemm_bf16<1><<<dim3(4, 64, 1), 256, 0, stream>>>(
        xb, WqT, bq, qbuf, 8192, 512, 512, 1, 512, 512, 512, 0, 0, 0);
    // conv: pconv[b*4+kc] = WcB[512][2048] @ xg[b]^T  (split-K 4, partials)
    gemm_bf16<0><<<dim3(8, 4, 8), 256, 0, stream>>>(
        WcB, xg, nullptr, pconv, 512, 1024, 512, 4, 2048, 2048, 1024,
        0, 2048l * 1024, 0);
    // fused partial-reduce + LN over m -> bf16
    ln_kernel<<<dim3(1024), 256, 0, stream>>>(pconv, xwb, gamma, beta);
    // KV: pkv[b*4+kc] = xwb[b] @ Wkv  (split-K 4, partials)
    gemm_bf16<0><<<dim3(8, 4, 8), 256, 0, stream>>>(
        xwb, WkvT, nullptr, pkv, 512, 1024, 256, 4, 1024, 1024, 1024,
        512l * 1024, 0, 0);
    // fused partial-reduce + bias + K/V layout
    kvpost_kernel<<<dim3(8, 8, 2), 256, 0, stream>>>(pkv, bkv, kbuf, vTb);
    // attention
    attn_kernel<<<dim3(32, 16), 256, 0, stream>>>(qbuf, kbuf, vTb, o2);
    // out = o2 @ Wproj + bproj (fp32)
    gemm_bf16<2><<<dim3(4, 64, 1), 256, 0, stream>>>(
        o2, WprojT, bproj, out, 8192, 512, 512, 1, 512, 512, 512, 0, 0, 0);
}

// Round 10
// 178.043 us; speedup vs baseline: 1.0437x; 1.0437x over previous
//
#include <hip/hip_runtime.h>

// ============================================================================
// 7-launch pipeline. All pieces are round-4-PASSED (180.2us) forms:
//  - prep_kernel   : fused converts + im2col (640 blocks)
//  - qconv_kernel  : NEW thin dispatcher fusing Q GEMM (1024 blocks) + conv
//                    GEMM (512 blocks) via block-range branching (prep-proven
//                    pattern); body = r4's gemm64 as a __device__ function
//  - ln_kernel     : 2-partial reduce + LN
//  - gemm64<0>     : KV GEMM (split-K 2)
//  - kvpost_kernel : 2-partial reduce + K/V layout
//  - attn_kernel   : flash-style attention
//  - gemm64<2>     : proj GEMM
// Conv bias skipped (constant over LN axis -> cancelled exactly by LN).
// NOTE: hipLaunchCooperativeKernel is a TRAP on this stack (r7/r8: zero
// output, absmax == max|ref|). Regular launches only.
// ============================================================================

#define B_    2
#define NTOK  4096
#define C_    512
#define MSP   1024

typedef __attribute__((ext_vector_type(8))) short short8;
typedef __attribute__((ext_vector_type(4))) short short4v;
typedef __attribute__((ext_vector_type(4))) float f32x4;

__device__ __forceinline__ unsigned short f2bf(float f) {
    unsigned u = __builtin_bit_cast(unsigned, f);
    u += 0x7FFFu + ((u >> 16) & 1u);            // RNE
    return (unsigned short)(u >> 16);
}

// ---------------------------------------------------------------------------
// Fused prep (one launch, 640 blocks) — round-4 verbatim.
// ---------------------------------------------------------------------------
__device__ __forceinline__ void tconv_dev(
    const float* __restrict__ in, unsigned short* __restrict__ out,
    int R, int C, int bx, int by, int tid, float (*T)[68])
{
    const int r0 = by * 64, c0 = bx * 64;
    const int i = tid >> 2, jp = tid & 3;
    #pragma unroll
    for (int q = 0; q < 4; ++q) {
        float4 v = *(const float4*)(in + (long)(r0 + i) * C + c0 + jp * 16 + q * 4);
        *(float4*)&T[i][jp * 16 + q * 4] = v;
    }
    __syncthreads();
    #pragma unroll
    for (int q = 0; q < 4; ++q) {
        short4v o;
        #pragma unroll
        for (int l = 0; l < 4; ++l)
            o[l] = (short)f2bf(T[jp * 16 + q * 4 + l][i]);
        *(short4v*)(out + (long)(c0 + i) * R + r0 + jp * 16 + q * 4) = o;
    }
}

__global__ __launch_bounds__(256) void prep_kernel(
    const float* __restrict__ x, unsigned short* __restrict__ xg,
    unsigned short* __restrict__ xb,
    const float* __restrict__ Wq,    unsigned short* __restrict__ WqT,
    const float* __restrict__ Wkv,   unsigned short* __restrict__ WkvT,
    const float* __restrict__ Wproj, unsigned short* __restrict__ WprojT,
    const float* __restrict__ Wconv, unsigned short* __restrict__ WcB)
{
    __shared__ float T[64][68];
    const int bx = blockIdx.x;
    const int tid = threadIdx.x;

    if (bx < 128) {
        const int b = bx >> 6;
        const int ty = tid >> 4, tx = tid & 15;
        const int m = (bx & 63) * 16 + ty;
        const int my = m >> 5, mx = m & 31;
        const float* xsrc = x + (long)b * NTOK * C_;
        unsigned short* op = xg + ((long)b * MSP + m) * 2048;
        unsigned short* xo = xb + (long)b * NTOK * C_;
        const int n00 = (2 * my) * 64 + 2 * mx;
        const int n01 = n00 + 1, n10 = n00 + 64, n11 = n00 + 65;
        const float* p00 = xsrc + (long)n00 * C_;
        const float* p01 = xsrc + (long)n01 * C_;
        const float* p10 = xsrc + (long)n10 * C_;
        const float* p11 = xsrc + (long)n11 * C_;
        for (int c0 = tx * 4; c0 < C_; c0 += 64) {
            float4 v0 = *(const float4*)(p00 + c0);
            float4 v1 = *(const float4*)(p01 + c0);
            float4 v2 = *(const float4*)(p10 + c0);
            float4 v3 = *(const float4*)(p11 + c0);
            short8 o0, o1;
            o0[0] = (short)f2bf(v0.x); o0[1] = (short)f2bf(v1.x);
            o0[2] = (short)f2bf(v2.x); o0[3] = (short)f2bf(v3.x);
            o0[4] = (short)f2bf(v0.y); o0[5] = (short)f2bf(v1.y);
            o0[6] = (short)f2bf(v2.y); o0[7] = (short)f2bf(v3.y);
            o1[0] = (short)f2bf(v0.z); o1[1] = (short)f2bf(v1.z);
            o1[2] = (short)f2bf(v2.z); o1[3] = (short)f2bf(v3.z);
            o1[4] = (short)f2bf(v0.w); o1[5] = (short)f2bf(v1.w);
            o1[6] = (short)f2bf(v2.w); o1[7] = (short)f2bf(v3.w);
            *(short8*)(op + 4 * c0) = o0;
            *(short8*)(op + 4 * c0 + 8) = o1;
            short4v s;
            s[0] = (short)f2bf(v0.x); s[1] = (short)f2bf(v0.y);
            s[2] = (short)f2bf(v0.z); s[3] = (short)f2bf(v0.w);
            *(short4v*)(xo + (long)n00 * C_ + c0) = s;
            s[0] = (short)f2bf(v1.x); s[1] = (short)f2bf(v1.y);
            s[2] = (short)f2bf(v1.z); s[3] = (short)f2bf(v1.w);
            *(short4v*)(xo + (long)n01 * C_ + c0) = s;
            s[0] = (short)f2bf(v2.x); s[1] = (short)f2bf(v2.y);
            s[2] = (short)f2bf(v2.z); s[3] = (short)f2bf(v2.w);
            *(short4v*)(xo + (long)n10 * C_ + c0) = s;
            s[0] = (short)f2bf(v3.x); s[1] = (short)f2bf(v3.y);
            s[2] = (short)f2bf(v3.z); s[3] = (short)f2bf(v3.w);
            *(short4v*)(xo + (long)n11 * C_ + c0) = s;
        }
    } else if (bx < 192) {
        int sb = bx - 128;
        tconv_dev(Wq, WqT, 512, 512, sb & 7, sb >> 3, tid, T);
    } else if (bx < 448) {
        int sb = bx - 192;
        tconv_dev(Wkv, WkvT, 1024, 1024, sb & 15, sb >> 4, tid, T);
    } else if (bx < 512) {
        int sb = bx - 448;
        tconv_dev(Wproj, WprojT, 512, 512, sb & 7, sb >> 3, tid, T);
    } else {
        int base = (bx - 512) * 256 + tid;   // 0..32767
        #pragma unroll
        for (int j = 0; j < 4; ++j) {
            int i = base + j * 32768;        // short8 index, 131072 total
            float4 a = ((const float4*)Wconv)[2 * i];
            float4 b = ((const float4*)Wconv)[2 * i + 1];
            short8 o;
            o[0] = (short)f2bf(a.x); o[1] = (short)f2bf(a.y);
            o[2] = (short)f2bf(a.z); o[3] = (short)f2bf(a.w);
            o[4] = (short)f2bf(b.x); o[5] = (short)f2bf(b.y);
            o[6] = (short)f2bf(b.z); o[7] = (short)f2bf(b.w);
            ((short8*)WcB)[i] = o;
        }
    }
}

// ---------------------------------------------------------------------------
// bf16 MFMA GEMM body — round-4 gemm64 verbatim, as a __device__ function.
// 64x64 tile, BK=64, 4 waves (32x32 wave tile, 2x2 frags).
// C[row][col] = sum_k A[row][k] * BT[col][k]
// OMODE: 0 = fp32 partial store at Cv + z*M*ldc (split-K, no bias),
//        1 = bf16 store + col bias, 2 = fp32 store + col bias.
// ---------------------------------------------------------------------------
template<int OMODE>
__device__ __forceinline__ void dev_gemm64(
    const unsigned short* __restrict__ A, const unsigned short* __restrict__ BT,
    const float* __restrict__ bias, void* __restrict__ Cv,
    int M, int N, int Kc, int KS, int lda, int ldb, int ldc,
    long sAb, long sBb, long sCb, int bx, int by, int z,
    unsigned short (*As)[72], unsigned short (*Bs)[72])
{
    const int tid = threadIdx.x;
    const int b = z / KS, kc = z % KS;
    const int row0 = by * 64, col0 = bx * 64;
    const unsigned short* Ap = A + b * sAb + (long)kc * Kc + (long)row0 * lda;
    const unsigned short* Bp = BT + b * sBb + (long)kc * Kc + (long)col0 * ldb;
    const int lane = tid & 63, wave = tid >> 6;
    const int wr = (wave >> 1) * 32, wc = (wave & 1) * 32;
    const int l15 = lane & 15, l4 = lane >> 4;

    f32x4 acc[2][2] = {};
    const int nk = Kc >> 6;
    for (int ks = 0; ks < nk; ++ks) {
        const int k0 = ks << 6;
        short8 ar[2], br[2];
        int rr[2], pp[2];
        #pragma unroll
        for (int i = 0; i < 2; ++i) {
            int chunk = tid + 256 * i;
            rr[i] = chunk >> 3; pp[i] = chunk & 7;
            ar[i] = *(const short8*)(Ap + (long)rr[i] * lda + k0 + pp[i] * 8);
            br[i] = *(const short8*)(Bp + (long)rr[i] * ldb + k0 + pp[i] * 8);
        }
        __syncthreads();   // prior reads of As/Bs complete
        #pragma unroll
        for (int i = 0; i < 2; ++i) {
            *(short8*)&As[rr[i]][pp[i] * 8] = ar[i];
            *(short8*)&Bs[rr[i]][pp[i] * 8] = br[i];
        }
        __syncthreads();
        #pragma unroll
        for (int kg = 0; kg < 2; ++kg) {
            short8 af[2], bf[2];
            #pragma unroll
            for (int mf = 0; mf < 2; ++mf)
                af[mf] = *(const short8*)&As[wr + mf * 16 + l15][kg * 32 + l4 * 8];
            #pragma unroll
            for (int nf = 0; nf < 2; ++nf)
                bf[nf] = *(const short8*)&Bs[wc + nf * 16 + l15][kg * 32 + l4 * 8];
            #pragma unroll
            for (int mf = 0; mf < 2; ++mf)
                #pragma unroll
                for (int nf = 0; nf < 2; ++nf)
                    acc[mf][nf] = __builtin_amdgcn_mfma_f32_16x16x32_bf16(
                        af[mf], bf[nf], acc[mf][nf], 0, 0, 0);
        }
    }
    // C/D frag layout: col = lane&15, row = (lane>>4)*4 + r  [verified]
    const int cb = col0 + wc + l15;
    const int rb = row0 + wr + l4 * 4;
    if (OMODE == 0) {
        float* C = (float*)Cv + (long)z * M * (long)ldc;
        #pragma unroll
        for (int mf = 0; mf < 2; ++mf)
            #pragma unroll
            for (int nf = 0; nf < 2; ++nf)
                #pragma unroll
                for (int i = 0; i < 4; ++i)
                    C[(long)(rb + mf * 16 + i) * ldc + cb + nf * 16] = acc[mf][nf][i];
    } else if (OMODE == 1) {
        unsigned short* C = (unsigned short*)Cv + sCb * b;
        #pragma unroll
        for (int nf = 0; nf < 2; ++nf) {
            float bv = bias[cb + nf * 16];
            #pragma unroll
            for (int mf = 0; mf < 2; ++mf)
                #pragma unroll
                for (int i = 0; i < 4; ++i)
                    C[(long)(rb + mf * 16 + i) * ldc + cb + nf * 16] =
                        f2bf(acc[mf][nf][i] + bv);
        }
    } else {
        float* C = (float*)Cv + sCb * b;
        #pragma unroll
        for (int nf = 0; nf < 2; ++nf) {
            float bv = bias[cb + nf * 16];
            #pragma unroll
            for (int mf = 0; mf < 2; ++mf)
                #pragma unroll
                for (int i = 0; i < 4; ++i)
                    C[(long)(rb + mf * 16 + i) * ldc + cb + nf * 16] =
                        acc[mf][nf][i] + bv;
        }
    }
}

// standalone wrapper (r4 launch-compatible)
template<int OMODE>
__global__ __launch_bounds__(256) void gemm64(
    const unsigned short* __restrict__ A, const unsigned short* __restrict__ BT,
    const float* __restrict__ bias, void* __restrict__ Cv,
    int M, int N, int Kc, int KS, int lda, int ldb, int ldc,
    long sAb, long sBb, long sCb)
{
    __shared__ unsigned short As[64][72];
    __shared__ unsigned short Bs[64][72];
    dev_gemm64<OMODE>(A, BT, bias, Cv, M, N, Kc, KS, lda, ldb, ldc,
                      sAb, sBb, sCb, blockIdx.x, blockIdx.y, blockIdx.z, As, Bs);
}

// ---------------------------------------------------------------------------
// Fused Q GEMM + conv GEMM dispatcher (1536 blocks, block-range branching):
//  [0,1024)    : Q = xb @ WqT + bq -> qbuf bf16        (bx=j&7, by=j>>3)
//  [1024,1536) : pconv[z] = WcB @ xg^T partials, KS=2  (bx=j&15, by=(j>>4)&7,
//                                                       z=j>>7 in [0,4))
// ---------------------------------------------------------------------------
__global__ __launch_bounds__(256) void qconv_kernel(
    const unsigned short* __restrict__ xb, const unsigned short* __restrict__ WqT,
    const float* __restrict__ bq, unsigned short* __restrict__ qbuf,
    const unsigned short* __restrict__ WcB, const unsigned short* __restrict__ xg,
    float* __restrict__ pconv)
{
    __shared__ unsigned short As[64][72];
    __shared__ unsigned short Bs[64][72];
    const int j = blockIdx.x;
    if (j < 1024) {
        dev_gemm64<1>(xb, WqT, bq, qbuf, 8192, 512, 512, 1, 512, 512, 512,
                      0, 0, 0, j & 7, j >> 3, 0, As, Bs);
    } else {
        const int j2 = j - 1024;
        dev_gemm64<0>(WcB, xg, nullptr, pconv, 512, 1024, 1024, 2,
                      2048, 2048, 1024, 0, 2048l * 1024, 0,
                      j2 & 15, (j2 >> 4) & 7, j2 >> 7, As, Bs);
    }
}

// ---------------------------------------------------------------------------
// Fused 2-partial reduce + LayerNorm over m (1024) -> bf16 — round-4 verbatim.
// ---------------------------------------------------------------------------
__global__ __launch_bounds__(256) void ln_kernel(
    const float* __restrict__ pconv, unsigned short* __restrict__ xwb,
    const float* __restrict__ gamma, const float* __restrict__ beta)
{
    __shared__ float red[256];
    const int tid = threadIdx.x;
    const int b = blockIdx.x >> 9, c = blockIdx.x & 511;
    const float* base = pconv + (long)b * 2 * 512 * 1024 + (long)c * 1024;
    const int m = tid * 4;
    float4 v;
    {
        float4 t0 = *(const float4*)(base + m);
        float4 t1 = *(const float4*)(base + 512 * 1024 + m);
        v.x = t0.x + t1.x; v.y = t0.y + t1.y;
        v.z = t0.z + t1.z; v.w = t0.w + t1.w;
    }
    red[tid] = v.x + v.y + v.z + v.w;
    __syncthreads();
    for (int off = 128; off > 0; off >>= 1) {
        if (tid < off) red[tid] += red[tid + off];
        __syncthreads();
    }
    float mu = red[0] * (1.0f / MSP);
    __syncthreads();
    float dx = v.x - mu, dy = v.y - mu, dz = v.z - mu, dw = v.w - mu;
    red[tid] = dx * dx + dy * dy + dz * dz + dw * dw;
    __syncthreads();
    for (int off = 128; off > 0; off >>= 1) {
        if (tid < off) red[tid] += red[tid + off];
        __syncthreads();
    }
    float rs = rsqrtf(red[0] * (1.0f / MSP) + 1e-5f);
    float4 g  = *(const float4*)(gamma + m);
    float4 be = *(const float4*)(beta + m);
    short4v o;
    o[0] = (short)f2bf(dx * rs * g.x + be.x);
    o[1] = (short)f2bf(dy * rs * g.y + be.y);
    o[2] = (short)f2bf(dz * rs * g.z + be.z);
    o[3] = (short)f2bf(dw * rs * g.w + be.w);
    *(short4v*)(xwb + (long)blockIdx.x * MSP + m) = o;
}

// ---------------------------------------------------------------------------
// Fused 2-partial reduce + kv post — round-4 verbatim.
// ---------------------------------------------------------------------------
__global__ __launch_bounds__(256) void kvpost_kernel(
    const float* __restrict__ pkv, const float* __restrict__ bkv,
    unsigned short* __restrict__ kbuf, unsigned short* __restrict__ vT)
{
    __shared__ float T[64][68];
    const int tid = threadIdx.x;
    const int m0 = blockIdx.x * 64, u0 = blockIdx.y * 64, b = blockIdx.z;
    const float* base = pkv + (long)b * 2 * 512 * 1024;
    const int i = tid >> 2, jp = tid & 3;
    #pragma unroll
    for (int q = 0; q < 4; ++q) {
        int uc = u0 + jp * 16 + q * 4;
        float4 bb = *(const float4*)(bkv + uc);
        float4 t0 = *(const float4*)(base + (long)(m0 + i) * 1024 + uc);
        float4 t1 = *(const float4*)(base + 512 * 1024 + (long)(m0 + i) * 1024 + uc);
        short4v o;
        o[0] = (short)f2bf(t0.x + t1.x + bb.x);
        o[1] = (short)f2bf(t0.y + t1.y + bb.y);
        o[2] = (short)f2bf(t0.z + t1.z + bb.z);
        o[3] = (short)f2bf(t0.w + t1.w + bb.w);
        *(short4v*)(kbuf + ((long)b * 512 + m0 + i) * 512 + uc) = o;
    }
    #pragma unroll
    for (int q = 0; q < 4; ++q) {
        int uc = u0 + jp * 16 + q * 4;
        float4 bb = *(const float4*)(bkv + 512 + uc);
        float4 t0 = *(const float4*)(base + (long)(m0 + i) * 1024 + 512 + uc);
        float4 t1 = *(const float4*)(base + 512 * 1024 + (long)(m0 + i) * 1024 + 512 + uc);
        float4 v;
        v.x = t0.x + t1.x + bb.x; v.y = t0.y + t1.y + bb.y;
        v.z = t0.z + t1.z + bb.z; v.w = t0.w + t1.w + bb.w;
        *(float4*)&T[i][jp * 16 + q * 4] = v;
    }
    __syncthreads();
    #pragma unroll
    for (int q = 0; q < 4; ++q) {
        short4v o;
        #pragma unroll
        for (int l = 0; l < 4; ++l)
            o[l] = (short)f2bf(T[jp * 16 + q * 4 + l][i]);
        *(short4v*)(vT + ((long)b * 512 + u0 + i) * 512 + m0 + jp * 16 + q * 4) = o;
    }
}

// ---------------------------------------------------------------------------
// Attention — round-4 verbatim. 128 q-rows/block, KV len 512 in 8 tiles.
// Output in reference transpose-reshape layout: o2[b][(h*64+d)*8+(n>>9)][n&511]
// ---------------------------------------------------------------------------
__global__ __launch_bounds__(256) void attn_kernel(
    const unsigned short* __restrict__ qb, const unsigned short* __restrict__ kbuf,
    const unsigned short* __restrict__ vT, unsigned short* __restrict__ o2)
{
    __shared__ unsigned short Qs[128][72];
    __shared__ unsigned short Ks[64][72];
    __shared__ unsigned short Vs[64][72];
    __shared__ unsigned short Ps[4][32][72];
    const int tid = threadIdx.x;
    const int b = blockIdx.y >> 3, h = blockIdx.y & 7;
    const int n0 = blockIdx.x * 128;
    const int lane = tid & 63, w = tid >> 6;
    const int l15 = lane & 15, l4 = lane >> 4;

    const unsigned short* Qg = qb + ((long)b * NTOK + n0) * 512 + h * 64;
    const unsigned short* Kg = kbuf + (long)b * 512 * 512 + h * 64;
    const unsigned short* Vg = vT + ((long)b * 512 + h * 64) * 512;

    #pragma unroll
    for (int it = 0; it < 4; ++it) {
        int chunk = tid + 256 * it;
        int r = chunk >> 3, p = chunk & 7;
        *(short8*)&Qs[r][p * 8] = *(const short8*)(Qg + (long)r * 512 + p * 8);
    }
    __syncthreads();
    short8 qa[2][2];
    #pragma unroll
    for (int mf = 0; mf < 2; ++mf)
        #pragma unroll
        for (int kg = 0; kg < 2; ++kg)
            qa[mf][kg] = *(const short8*)&Qs[w * 32 + mf * 16 + l15][kg * 32 + l4 * 8];

    f32x4 oacc[2][4] = {};
    float lsum[2][4] = {};

    for (int mt = 0; mt < 8; ++mt) {
        const int m0 = mt * 64;
        __syncthreads();
        #pragma unroll
        for (int it = 0; it < 2; ++it) {
            int chunk = tid + 256 * it;
            int r = chunk >> 3, p = chunk & 7;
            *(short8*)&Ks[r][p * 8] = *(const short8*)(Kg + (long)(m0 + r) * 512 + p * 8);
            *(short8*)&Vs[r][p * 8] = *(const short8*)(Vg + (long)r * 512 + m0 + p * 8);
        }
        __syncthreads();
        f32x4 s[2][4];
        #pragma unroll
        for (int nf = 0; nf < 4; ++nf) {
            short8 kb0 = *(const short8*)&Ks[nf * 16 + l15][l4 * 8];
            short8 kb1 = *(const short8*)&Ks[nf * 16 + l15][32 + l4 * 8];
            #pragma unroll
            for (int mf = 0; mf < 2; ++mf) {
                f32x4 zz = {};
                zz = __builtin_amdgcn_mfma_f32_16x16x32_bf16(qa[mf][0], kb0, zz, 0, 0, 0);
                zz = __builtin_amdgcn_mfma_f32_16x16x32_bf16(qa[mf][1], kb1, zz, 0, 0, 0);
                s[mf][nf] = zz;
            }
        }
        #pragma unroll
        for (int mf = 0; mf < 2; ++mf)
            #pragma unroll
            for (int nf = 0; nf < 4; ++nf)
                #pragma unroll
                for (int i = 0; i < 4; ++i) {
                    float pv = __expf(s[mf][nf][i] * 0.125f);
                    lsum[mf][i] += pv;
                    Ps[w][mf * 16 + l4 * 4 + i][nf * 16 + l15] = f2bf(pv);
                }
        #pragma unroll
        for (int mf = 0; mf < 2; ++mf) {
            short8 pa0 = *(const short8*)&Ps[w][mf * 16 + l15][l4 * 8];
            short8 pa1 = *(const short8*)&Ps[w][mf * 16 + l15][32 + l4 * 8];
            #pragma unroll
            for (int df = 0; df < 4; ++df) {
                short8 vb0 = *(const short8*)&Vs[df * 16 + l15][l4 * 8];
                short8 vb1 = *(const short8*)&Vs[df * 16 + l15][32 + l4 * 8];
                oacc[mf][df] = __builtin_amdgcn_mfma_f32_16x16x32_bf16(pa0, vb0, oacc[mf][df], 0, 0, 0);
                oacc[mf][df] = __builtin_amdgcn_mfma_f32_16x16x32_bf16(pa1, vb1, oacc[mf][df], 0, 0, 0);
            }
        }
    }
    #pragma unroll
    for (int mf = 0; mf < 2; ++mf)
        #pragma unroll
        for (int i = 0; i < 4; ++i) {
            float v = lsum[mf][i];
            v += __shfl_xor(v, 1, 64);
            v += __shfl_xor(v, 2, 64);
            v += __shfl_xor(v, 4, 64);
            v += __shfl_xor(v, 8, 64);
            lsum[mf][i] = 1.0f / v;
        }
    const int nhi = n0 >> 9;
    const int colb = (n0 & 511) + w * 32;
    #pragma unroll
    for (int mf = 0; mf < 2; ++mf)
        #pragma unroll
        for (int df = 0; df < 4; ++df) {
            int d = h * 64 + df * 16 + l15;
            long row = (long)b * NTOK + (long)d * 8 + nhi;
            short4v o;
            o[0] = (short)f2bf(oacc[mf][df][0] * lsum[mf][0]);
            o[1] = (short)f2bf(oacc[mf][df][1] * lsum[mf][1]);
            o[2] = (short)f2bf(oacc[mf][df][2] * lsum[mf][2]);
            o[3] = (short)f2bf(oacc[mf][df][3] * lsum[mf][3]);
            *(short4v*)(o2 + row * 512 + colb + mf * 16 + l4 * 4) = o;
        }
}

// ---------------------------------------------------------------------------
extern "C" void kernel_launch(void* const* d_in, const int* in_sizes, int n_in,
                              void* d_out, int out_size, void* d_ws, size_t ws_size,
                              hipStream_t stream)
{
    (void)in_sizes; (void)n_in; (void)out_size; (void)ws_size;
    const float* x     = (const float*)d_in[0];
    const float* Wq    = (const float*)d_in[1];
    const float* bq    = (const float*)d_in[2];
    const float* Wconv = (const float*)d_in[3];
    // d_in[4] = bconv: constant over LN axis -> exactly cancelled by LN; unused
    const float* gamma = (const float*)d_in[5];
    const float* beta  = (const float*)d_in[6];
    const float* Wkv   = (const float*)d_in[7];
    const float* bkv   = (const float*)d_in[8];
    const float* Wproj = (const float*)d_in[9];
    const float* bproj = (const float*)d_in[10];
    float* out = (float*)d_out;
    char* ws = (char*)d_ws;

    unsigned short* xb     = (unsigned short*)(ws);                  //  8 MB
    unsigned short* qbuf   = (unsigned short*)(ws + (8ul  << 20));   //  8 MB
    unsigned short* xg     = (unsigned short*)(ws + (16ul << 20));   //  8 MB
    unsigned short* o2     = xg;                                     //  overlay
    unsigned short* WqT    = (unsigned short*)(ws + (24ul << 20));   // 0.5 MB
    unsigned short* WcB    = (unsigned short*)(ws + (25ul << 20));   //  2 MB
    unsigned short* WkvT   = (unsigned short*)(ws + (27ul << 20));   //  2 MB
    unsigned short* WprojT = (unsigned short*)(ws + (29ul << 20));   // 0.5 MB
    float*          pconv  = (float*)         (ws + (30ul << 20));   //  8 MB
    unsigned short* xwb    = (unsigned short*)(ws + (46ul << 20));   //  2 MB
    float*          pkv    = (float*)         (ws + (48ul << 20));   //  8 MB
    unsigned short* kbuf   = (unsigned short*)(ws + (64ul << 20));   //  1 MB
    unsigned short* vTb    = (unsigned short*)(ws + (65ul << 20));   //  1 MB

    // all prep in one launch
    prep_kernel<<<dim3(640), 256, 0, stream>>>(
        x, xg, xb, Wq, WqT, Wkv, WkvT, Wproj, WprojT, Wconv, WcB);
    // Q GEMM + conv GEMM fused in one launch (1536 blocks, 6/CU)
    qconv_kernel<<<dim3(1536), 256, 0, stream>>>(
        xb, WqT, bq, qbuf, WcB, xg, pconv);
    // fused partial-reduce + LN over m -> bf16
    ln_kernel<<<dim3(1024), 256, 0, stream>>>(pconv, xwb, gamma, beta);
    // KV: pkv[z] = xwb[b] @ Wkv (split-K 2)  512 blocks
    gemm64<0><<<dim3(16, 8, 4), 256, 0, stream>>>(
        xwb, WkvT, nullptr, pkv, 512, 1024, 512, 2, 1024, 1024, 1024,
        512l * 1024, 0, 0);
    // fused partial-reduce + bias + K/V layout
    kvpost_kernel<<<dim3(8, 8, 2), 256, 0, stream>>>(pkv, bkv, kbuf, vTb);
    // attention
    attn_kernel<<<dim3(32, 16), 256, 0, stream>>>(qbuf, kbuf, vTb, o2);
    // out = o2 @ Wproj + bproj (fp32)   (1024 blocks, 4/CU)
    gemm64<2><<<dim3(8, 128, 1), 256, 0, stream>>>(
        o2, WprojT, bproj, out, 8192, 512, 512, 1, 512, 512, 512, 0, 0, 0);
}